// Round 4
// baseline (1307.950 us; speedup 1.0000x reference)
//
#include <hip/hip_runtime.h>
#include <hip/hip_fp16.h>
#include <cstdint>
#include <cstddef>

#define Bn 4
#define Hn 16
#define Sn 2048
#define Dn 128

typedef _Float16 half8  __attribute__((ext_vector_type(8)));
typedef float    f32x16 __attribute__((ext_vector_type(16)));
typedef unsigned uint4v __attribute__((ext_vector_type(4)));

__device__ __forceinline__ int pk_f16(float a, float b){
  auto h = __builtin_amdgcn_cvt_pkrtz(a, b);   // __fp16x2
  return __builtin_bit_cast(int, h);
}

// ---------------- prep kernels ----------------

__global__ void k_rope_table(float2* __restrict__ tab){
  const int idx = blockIdx.x*256 + threadIdx.x;     // [s][i], 2048*64
  const int i = idx & 63, s = idx >> 6;
  const double invf = exp(-(double)i * (9.210340371976184 / 64.0)); // 10000^(-i/64)
  const double ang  = (double)s * invf;
  float2 cs; cs.x = (float)cos(ang); cs.y = (float)sin(ang);
  tab[idx] = cs;
}

// Pack Q,K into MFMA-fragment order with rope applied.
// Chunk t = ((bh*64 + blk)*8 + dc)*64 + lane; lane = ln+32h holds
// row s = blk*32+ln, d-range dc*16 + h*8 (8 halfs = 16B).
__global__ void k_pack_qk(const float* __restrict__ q, const float* __restrict__ k,
                          const float2* __restrict__ tab,
                          half8* __restrict__ qp, half8* __restrict__ kp){
  const int t    = blockIdx.x*256 + threadIdx.x;    // 2,097,152 chunks
  const int lane = t & 63, ln = lane & 31, h = lane >> 5;
  const int dc   = (t >> 6) & 7;
  const int blk  = (t >> 9) & 63;
  const int bh   = t >> 15;
  const int s    = blk*32 + ln;
  const size_t roff = ((size_t)bh*Sn + s)*Dn + dc*16 + h*8;
  const float4 a0 = *(const float4*)(q + roff);
  const float4 a1 = *(const float4*)(q + roff + 4);
  const float4 b0 = *(const float4*)(k + roff);
  const float4 b1 = *(const float4*)(k + roff + 4);
  const float2* tb = tab + s*64 + dc*8 + h*4;
  const float2 c0 = tb[0], c1 = tb[1], c2 = tb[2], c3 = tb[3];
  const float SC = 0.08838834764831845f;            // 1/sqrt(128) folded into q
  half8 qo, ko;
  qo[0] = (_Float16)((a0.x*c0.x - a0.y*c0.y)*SC);
  qo[1] = (_Float16)((a0.y*c0.x + a0.x*c0.y)*SC);
  qo[2] = (_Float16)((a0.z*c1.x - a0.w*c1.y)*SC);
  qo[3] = (_Float16)((a0.w*c1.x + a0.z*c1.y)*SC);
  qo[4] = (_Float16)((a1.x*c2.x - a1.y*c2.y)*SC);
  qo[5] = (_Float16)((a1.y*c2.x + a1.x*c2.y)*SC);
  qo[6] = (_Float16)((a1.z*c3.x - a1.w*c3.y)*SC);
  qo[7] = (_Float16)((a1.w*c3.x + a1.z*c3.y)*SC);
  ko[0] = (_Float16)(b0.x*c0.x - b0.y*c0.y);
  ko[1] = (_Float16)(b0.y*c0.x + b0.x*c0.y);
  ko[2] = (_Float16)(b0.z*c1.x - b0.w*c1.y);
  ko[3] = (_Float16)(b0.w*c1.x + b0.z*c1.y);
  ko[4] = (_Float16)(b1.x*c2.x - b1.y*c2.y);
  ko[5] = (_Float16)(b1.y*c2.x + b1.x*c2.y);
  ko[6] = (_Float16)(b1.z*c3.x - b1.w*c3.y);
  ko[7] = (_Float16)(b1.w*c3.x + b1.z*c3.y);
  qp[t] = qo;
  kp[t] = ko;
}

// Pack V^T into PV A-fragment order.
// Chunk t = ((bh*128 + k16)*4 + dt)*64 + lane; lane = ln+32h holds
// V[k16*16 + h*8 + j][dt*32 + ln], j = 0..7.
__global__ void k_pack_v(const float* __restrict__ v, half8* __restrict__ vp){
  const int t    = blockIdx.x*256 + threadIdx.x;    // 2,097,152 chunks
  const int lane = t & 63, ln = lane & 31, h = lane >> 5;
  const int dt   = (t >> 6) & 3;
  const int k16  = (t >> 8) & 127;
  const int bh   = t >> 15;
  const size_t base = ((size_t)bh*Sn + k16*16 + h*8)*Dn + dt*32 + ln;
  half8 o;
#pragma unroll
  for (int j = 0; j < 8; ++j) o[j] = (_Float16)v[base + (size_t)j*Dn];
  vp[t] = o;
}

__global__ void k_maskbits(const int* __restrict__ mask, unsigned* __restrict__ mtb){
  const int g = blockIdx.x*256 + threadIdx.x;       // [q32][k], 64*2048
  const int k = g & (Sn-1), q32 = g >> 11;
  unsigned bits = 0u;
  for (int j = 0; j < 32; ++j)
    bits |= (mask[(size_t)(q32*32 + j)*Sn + k] != 0 ? 1u : 0u) << j;
  mtb[g] = bits;
}

// ---------------- pass A: per-row softmax stats (m, L) ----------------
// grid 512 = BH*8; block 512 = 8 waves. Wave w -> qb = (work&7)*8 + w.
// Wave streams all 64 k-tiles with online max/sum; no LDS, no barriers.
// Lane holds q = ln; cols (r&3)+8*(r>>2)+4h per tile; halves merged at end.

__global__ __launch_bounds__(512, 3) void attn_stats(
    const half8* __restrict__ qp, const half8* __restrict__ kp,
    const unsigned* __restrict__ mtb, float2* __restrict__ mL)
{
  const int bid  = blockIdx.x;
  const int work = ((bid & 7) << 6) + (bid >> 3);   // XCD-contiguous bh ranges
  const int bh   = work >> 3;
  const int qg   = work & 7;
  const int w    = threadIdx.x >> 6;
  const int l    = threadIdx.x & 63;
  const int ln   = l & 31;
  const int h    = l >> 5;
  const int qb   = qg*8 + w;

  half8 qf[8];
#pragma unroll
  for (int dc = 0; dc < 8; ++dc)
    qf[dc] = qp[(((size_t)bh*64 + qb)*8 + dc)*64 + l];

  const unsigned* mrow = mtb + (size_t)qb*Sn;
  float m = -3.0e38f, L = 0.f;

  for (int kt = 0; kt < 64; ++kt){
    const half8* kf = kp + (((size_t)bh*64 + kt)*8)*64 + l;
    f32x16 a;
#pragma unroll
    for (int i = 0; i < 16; ++i) a[i] = 0.f;
#pragma unroll
    for (int dc = 0; dc < 8; ++dc)
      a = __builtin_amdgcn_mfma_f32_32x32x16_f16(kf[(size_t)dc*64], qf[dc], a, 0, 0, 0);

    float mt = -3.0e38f;
#pragma unroll
    for (int mm = 0; mm < 4; ++mm){
      const uint4v dw = *(const uint4v*)(mrow + kt*32 + mm*8 + h*4);
#pragma unroll
      for (int aa = 0; aa < 4; ++aa){
        const int r = mm*4 + aa;
        float s = ((dw[aa] >> ln) & 1u) ? a[r] : -1.0e30f;
        a[r] = s;
        mt = fmaxf(mt, s);
      }
    }
    const float mn = fmaxf(m, mt);
    L *= __expf(m - mn);
#pragma unroll
    for (int r = 0; r < 16; ++r) L += __expf(a[r] - mn);
    m = mn;
  }

  const float mo = __shfl_xor(m, 32, 64);
  const float Lo = __shfl_xor(L, 32, 64);
  const float mn = fmaxf(m, mo);
  const float Lc = L*__expf(m - mn) + Lo*__expf(mo - mn);
  if (l < 32){
    float2 st; st.x = mn; st.y = Lc;
    mL[(size_t)bh*Sn + qb*32 + ln] = st;
  }
}

// ---------------- pass B: store p + PV, stats precomputed ----------------
// grid 512 = BH*8; block 512 = 8 waves. Wave w -> qb = (work&7)*8 + w owns
// the full 32q x 2048k strip: recompute QK^T (bitwise same as pass A),
// p = exp(s-m)/L, store p via per-wave LDS transpose (full 128B lines),
// PV into private oacc, final out store via same LDS transpose. No barriers.

__global__ __launch_bounds__(512, 2) void attn_pv(
    const half8* __restrict__ qp, const half8* __restrict__ kp,
    const half8* __restrict__ vp, const unsigned* __restrict__ mtb,
    const float2* __restrict__ mL,
    float* __restrict__ out, float* __restrict__ pout)
{
  __shared__ float pt[8][32][34];

  const int bid  = blockIdx.x;
  const int work = ((bid & 7) << 6) + (bid >> 3);
  const int bh   = work >> 3;
  const int qg   = work & 7;
  const int w    = threadIdx.x >> 6;
  const int l    = threadIdx.x & 63;
  const int ln   = l & 31;
  const int h    = l >> 5;
  const int qb   = qg*8 + w;

  half8 qf[8];
#pragma unroll
  for (int dc = 0; dc < 8; ++dc)
    qf[dc] = qp[(((size_t)bh*64 + qb)*8 + dc)*64 + l];

  const float2 st = mL[(size_t)bh*Sn + qb*32 + ln];
  const float m    = st.x;
  const float rinv = 1.0f / st.y;

  f32x16 oacc[4];
#pragma unroll
  for (int dt = 0; dt < 4; ++dt)
#pragma unroll
    for (int i = 0; i < 16; ++i) oacc[dt][i] = 0.f;

  const unsigned* mrow = mtb + (size_t)qb*Sn;
  float* pbase = pout + ((size_t)bh*Sn + qb*32)*Sn;
  const int rq = l >> 3;          // transposed-store row within 8-row group
  const int rc = (l & 7) * 4;     // 4-float col offset

  for (int kt = 0; kt < 64; ++kt){
    // QK^T tile (identical sequence to pass A)
    const half8* kf = kp + (((size_t)bh*64 + kt)*8)*64 + l;
    f32x16 a;
#pragma unroll
    for (int i = 0; i < 16; ++i) a[i] = 0.f;
#pragma unroll
    for (int dc = 0; dc < 8; ++dc)
      a = __builtin_amdgcn_mfma_f32_32x32x16_f16(kf[(size_t)dc*64], qf[dc], a, 0, 0, 0);

    // mask + p = exp(s-m)/L -> pt[w][q=ln][col]
#pragma unroll
    for (int mm = 0; mm < 4; ++mm){
      const uint4v dw = *(const uint4v*)(mrow + kt*32 + mm*8 + h*4);
#pragma unroll
      for (int aa = 0; aa < 4; ++aa){
        const int r = mm*4 + aa;
        const float s = ((dw[aa] >> ln) & 1u) ? a[r] : -1.0e30f;
        a[r] = __expf(s - m) * rinv;
      }
    }
#pragma unroll
    for (int g = 0; g < 4; ++g){
      const int c = g*8 + h*4;
      float2 e0, e1;
      e0.x = a[4*g+0]; e0.y = a[4*g+1];
      e1.x = a[4*g+2]; e1.y = a[4*g+3];
      *(float2*)&pt[w][ln][c]   = e0;
      *(float2*)&pt[w][ln][c+2] = e1;
    }
    // transposed full-line p store
#pragma unroll
    for (int i = 0; i < 4; ++i){
      const int qq = i*8 + rq;
      const float2 t0 = *(const float2*)&pt[w][qq][rc];
      const float2 t1 = *(const float2*)&pt[w][qq][rc+2];
      float4 o4; o4.x = t0.x; o4.y = t0.y; o4.z = t1.x; o4.w = t1.y;
      *(float4*)(pbase + (size_t)qq*Sn + kt*32 + rc) = o4;
    }
    // PV: B-frag from pt, A-frag = packed V^T
#pragma unroll
    for (int t16 = 0; t16 < 2; ++t16){
      const int c = t16*16 + h*8;
      const float2 b0 = *(const float2*)&pt[w][ln][c];
      const float2 b1 = *(const float2*)&pt[w][ln][c+2];
      const float2 b2 = *(const float2*)&pt[w][ln][c+4];
      const float2 b3 = *(const float2*)&pt[w][ln][c+6];
      int4 bi;
      bi.x = pk_f16(b0.x, b0.y);
      bi.y = pk_f16(b1.x, b1.y);
      bi.z = pk_f16(b2.x, b2.y);
      bi.w = pk_f16(b3.x, b3.y);
      const half8 bf = __builtin_bit_cast(half8, bi);
      const half8* vf = vp + (((size_t)bh*128 + (kt*2 + t16))*4)*64 + l;
#pragma unroll
      for (int dt = 0; dt < 4; ++dt)
        oacc[dt] = __builtin_amdgcn_mfma_f32_32x32x16_f16(vf[(size_t)dt*64], bf, oacc[dt], 0, 0, 0);
    }
  }

  // out store via same per-wave LDS transpose (full 128B lines per row)
  const size_t obase = ((size_t)bh*Sn + qb*32)*Dn;
#pragma unroll
  for (int dt = 0; dt < 4; ++dt){
#pragma unroll
    for (int g = 0; g < 4; ++g){
      const int c = g*8 + h*4;
      float2 e0, e1;
      e0.x = oacc[dt][4*g+0]; e0.y = oacc[dt][4*g+1];
      e1.x = oacc[dt][4*g+2]; e1.y = oacc[dt][4*g+3];
      *(float2*)&pt[w][ln][c]   = e0;
      *(float2*)&pt[w][ln][c+2] = e1;
    }
#pragma unroll
    for (int i = 0; i < 4; ++i){
      const int qq = i*8 + rq;
      const float2 t0 = *(const float2*)&pt[w][qq][rc];
      const float2 t1 = *(const float2*)&pt[w][qq][rc+2];
      float4 o4; o4.x = t0.x; o4.y = t0.y; o4.z = t1.x; o4.w = t1.y;
      *(float4*)(out + obase + (size_t)qq*Dn + dt*32 + rc) = o4;
    }
  }
}

// ---------------- launch ----------------

extern "C" void kernel_launch(void* const* d_in, const int* in_sizes, int n_in,
                              void* d_out, int out_size, void* d_ws, size_t ws_size,
                              hipStream_t stream)
{
  const float* dq = (const float*)d_in[0];
  const float* dk = (const float*)d_in[1];
  const float* dv = (const float*)d_in[2];
  const int*   dm = (const int*)d_in[3];

  char* ws = (char*)d_ws;
  float2*   tab = (float2*)ws;                                  // 1 MiB
  half8*    qp  = (half8*)(ws + (size_t)(1u<<20));              // 32 MiB
  half8*    kp  = (half8*)(ws + (size_t)(1u<<20) + ((size_t)32<<20));
  half8*    vp  = (half8*)(ws + (size_t)(1u<<20) + ((size_t)64<<20));
  unsigned* mtb = (unsigned*)(ws + (size_t)(1u<<20) + ((size_t)96<<20));   // 0.5 MiB
  float2*   mLb = (float2*)(ws + (size_t)(1u<<20) + ((size_t)97<<20));     // 1 MiB

  float* out  = (float*)d_out;
  float* pout = out + (size_t)Bn*Hn*Sn*Dn;

  k_rope_table<<<512,  256, 0, stream>>>(tab);
  k_pack_qk   <<<8192, 256, 0, stream>>>(dq, dk, tab, qp, kp);
  k_pack_v    <<<8192, 256, 0, stream>>>(dv, vp);
  k_maskbits  <<<512,  256, 0, stream>>>(dm, mtb);
  attn_stats  <<<512,  512, 0, stream>>>(qp, kp, mtb, mLb);
  attn_pv     <<<512,  512, 0, stream>>>(qp, kp, vp, mtb, mLb, out, pout);
}

// Round 6
// 1172.928 us; speedup vs baseline: 1.1151x; 1.1151x over previous
//
#include <hip/hip_runtime.h>
#include <hip/hip_fp16.h>
#include <cstdint>
#include <cstddef>

#define Bn 4
#define Hn 16
#define Sn 2048
#define Dn 128

typedef _Float16 half8  __attribute__((ext_vector_type(8)));
typedef float    f32x16 __attribute__((ext_vector_type(16)));
typedef float    f32x4v __attribute__((ext_vector_type(4)));
typedef unsigned uint4v __attribute__((ext_vector_type(4)));

#define PSTR 268   // LDS row stride (floats): %4==0 (16B rows), 4-way banks worst case

__device__ __forceinline__ int pk_f16(float a, float b){
  auto h = __builtin_amdgcn_cvt_pkrtz(a, b);   // __fp16x2
  return __builtin_bit_cast(int, h);
}

// ---------------- prep kernels ----------------

__global__ void k_rope_table(float2* __restrict__ tab){
  const int idx = blockIdx.x*256 + threadIdx.x;     // [s][i], 2048*64
  const int i = idx & 63, s = idx >> 6;
  const double invf = exp(-(double)i * (9.210340371976184 / 64.0)); // 10000^(-i/64)
  const double ang  = (double)s * invf;
  float2 cs; cs.x = (float)cos(ang); cs.y = (float)sin(ang);
  tab[idx] = cs;
}

// Pack Q,K into MFMA-fragment order with rope applied.
__global__ void k_pack_qk(const float* __restrict__ q, const float* __restrict__ k,
                          const float2* __restrict__ tab,
                          half8* __restrict__ qp, half8* __restrict__ kp){
  const int t    = blockIdx.x*256 + threadIdx.x;    // 2,097,152 chunks
  const int lane = t & 63, ln = lane & 31, h = lane >> 5;
  const int dc   = (t >> 6) & 7;
  const int blk  = (t >> 9) & 63;
  const int bh   = t >> 15;
  const int s    = blk*32 + ln;
  const size_t roff = ((size_t)bh*Sn + s)*Dn + dc*16 + h*8;
  const float4 a0 = *(const float4*)(q + roff);
  const float4 a1 = *(const float4*)(q + roff + 4);
  const float4 b0 = *(const float4*)(k + roff);
  const float4 b1 = *(const float4*)(k + roff + 4);
  const float2* tb = tab + s*64 + dc*8 + h*4;
  const float2 c0 = tb[0], c1 = tb[1], c2 = tb[2], c3 = tb[3];
  const float SC = 0.08838834764831845f;            // 1/sqrt(128) folded into q
  half8 qo, ko;
  qo[0] = (_Float16)((a0.x*c0.x - a0.y*c0.y)*SC);
  qo[1] = (_Float16)((a0.y*c0.x + a0.x*c0.y)*SC);
  qo[2] = (_Float16)((a0.z*c1.x - a0.w*c1.y)*SC);
  qo[3] = (_Float16)((a0.w*c1.x + a0.z*c1.y)*SC);
  qo[4] = (_Float16)((a1.x*c2.x - a1.y*c2.y)*SC);
  qo[5] = (_Float16)((a1.y*c2.x + a1.x*c2.y)*SC);
  qo[6] = (_Float16)((a1.z*c3.x - a1.w*c3.y)*SC);
  qo[7] = (_Float16)((a1.w*c3.x + a1.z*c3.y)*SC);
  ko[0] = (_Float16)(b0.x*c0.x - b0.y*c0.y);
  ko[1] = (_Float16)(b0.y*c0.x + b0.x*c0.y);
  ko[2] = (_Float16)(b0.z*c1.x - b0.w*c1.y);
  ko[3] = (_Float16)(b0.w*c1.x + b0.z*c1.y);
  ko[4] = (_Float16)(b1.x*c2.x - b1.y*c2.y);
  ko[5] = (_Float16)(b1.y*c2.x + b1.x*c2.y);
  ko[6] = (_Float16)(b1.z*c3.x - b1.w*c3.y);
  ko[7] = (_Float16)(b1.w*c3.x + b1.z*c3.y);
  qp[t] = qo;
  kp[t] = ko;
}

// Pack V^T into PV A-fragment order.
__global__ void k_pack_v(const float* __restrict__ v, half8* __restrict__ vp){
  const int t    = blockIdx.x*256 + threadIdx.x;    // 2,097,152 chunks
  const int lane = t & 63, ln = lane & 31, h = lane >> 5;
  const int dt   = (t >> 6) & 3;
  const int k16  = (t >> 8) & 127;
  const int bh   = t >> 15;
  const size_t base = ((size_t)bh*Sn + k16*16 + h*8)*Dn + dt*32 + ln;
  half8 o;
#pragma unroll
  for (int j = 0; j < 8; ++j) o[j] = (_Float16)v[base + (size_t)j*Dn];
  vp[t] = o;
}

__global__ void k_maskbits(const int* __restrict__ mask, unsigned* __restrict__ mtb){
  const int g = blockIdx.x*256 + threadIdx.x;       // [q32][k], 64*2048
  const int k = g & (Sn-1), q32 = g >> 11;
  unsigned bits = 0u;
  for (int j = 0; j < 32; ++j)
    bits |= (mask[(size_t)(q32*32 + j)*Sn + k] != 0 ? 1u : 0u) << j;
  mtb[g] = bits;
}

// ---------------- pass A: per-row softmax stats (m, L) ----------------

__global__ __launch_bounds__(512, 3) void attn_stats(
    const half8* __restrict__ qp, const half8* __restrict__ kp,
    const unsigned* __restrict__ mtb, float2* __restrict__ mL)
{
  const int bid  = blockIdx.x;
  const int work = ((bid & 7) << 6) + (bid >> 3);   // XCD-contiguous bh ranges
  const int bh   = work >> 3;
  const int qg   = work & 7;
  const int w    = threadIdx.x >> 6;
  const int l    = threadIdx.x & 63;
  const int ln   = l & 31;
  const int h    = l >> 5;
  const int qb   = qg*8 + w;

  half8 qf[8];
#pragma unroll
  for (int dc = 0; dc < 8; ++dc)
    qf[dc] = qp[(((size_t)bh*64 + qb)*8 + dc)*64 + l];

  const unsigned* mrow = mtb + (size_t)qb*Sn;
  float m = -3.0e38f, L = 0.f;

  for (int kt = 0; kt < 64; ++kt){
    const half8* kf = kp + (((size_t)bh*64 + kt)*8)*64 + l;
    f32x16 a;
#pragma unroll
    for (int i = 0; i < 16; ++i) a[i] = 0.f;
#pragma unroll
    for (int dc = 0; dc < 8; ++dc)
      a = __builtin_amdgcn_mfma_f32_32x32x16_f16(kf[(size_t)dc*64], qf[dc], a, 0, 0, 0);

    float mt = -3.0e38f;
#pragma unroll
    for (int mm = 0; mm < 4; ++mm){
      const uint4v dw = *(const uint4v*)(mrow + kt*32 + mm*8 + h*4);
#pragma unroll
      for (int aa = 0; aa < 4; ++aa){
        const int r = mm*4 + aa;
        float s = ((dw[aa] >> ln) & 1u) ? a[r] : -1.0e30f;
        a[r] = s;
        mt = fmaxf(mt, s);
      }
    }
    const float mn = fmaxf(m, mt);
    L *= __expf(m - mn);
#pragma unroll
    for (int r = 0; r < 16; ++r) L += __expf(a[r] - mn);
    m = mn;
  }

  const float mo = __shfl_xor(m, 32, 64);
  const float Lo = __shfl_xor(L, 32, 64);
  const float mn = fmaxf(m, mo);
  const float Lc = L*__expf(m - mn) + Lo*__expf(mo - mn);
  if (l < 32){
    float2 st; st.x = mn; st.y = Lc;
    mL[(size_t)bh*Sn + qb*32 + ln] = st;
  }
}

// ---------------- pass B: store p + PV, burst-buffered in LDS ----------------
// grid 4096 = BH*64 strips; block 512 = 8 waves sharing ONE 32-row q strip.
// 8 groups of 256 cols: wave w computes kt = g*8+w into shared ps[32][PSTR],
// barrier, each wave streams 4 full 1KB row-segments (nt stores), PV from ps,
// barrier. Final: cross-wave LDS atomic reduce of out^T, coalesced nt store.

__global__ __launch_bounds__(512, 2) void attn_pv(
    const half8* __restrict__ qp, const half8* __restrict__ kp,
    const half8* __restrict__ vp, const unsigned* __restrict__ mtb,
    const float2* __restrict__ mL,
    float* __restrict__ out, float* __restrict__ pout)
{
  __shared__ float ps[32][PSTR];     // 33.5 KB: p strip, 32 rows x 256 cols
  __shared__ float lds_out[128*33];  // 16.9 KB: out^T reduction

  const int bid  = blockIdx.x;
  const int work = ((bid & 7) << 9) + (bid >> 3);   // XCD-contiguous bh ranges
  const int bh   = work >> 6;
  const int qb   = work & 63;
  const int tid  = threadIdx.x;
  const int w    = tid >> 6;
  const int l    = tid & 63;
  const int ln   = l & 31;
  const int h    = l >> 5;

  for (int i = tid; i < 128*33; i += 512) lds_out[i] = 0.f;

  half8 qf[8];
#pragma unroll
  for (int dc = 0; dc < 8; ++dc)
    qf[dc] = qp[(((size_t)bh*64 + qb)*8 + dc)*64 + l];

  const float2 st = mL[(size_t)bh*Sn + qb*32 + ln];
  const float m    = st.x;
  const float rinv = 1.0f / st.y;

  f32x16 oacc[4];
#pragma unroll
  for (int dt = 0; dt < 4; ++dt)
#pragma unroll
    for (int i = 0; i < 16; ++i) oacc[dt][i] = 0.f;

  const unsigned* mrow = mtb + (size_t)qb*Sn;
  float* pbase = pout + ((size_t)bh*Sn + qb*32)*Sn;

  for (int g = 0; g < 8; ++g){
    const int kt = g*8 + w;

    // QK^T tile (bitwise-identical MFMA sequence to pass A)
    const half8* kf = kp + (((size_t)bh*64 + kt)*8)*64 + l;
    f32x16 a;
#pragma unroll
    for (int i = 0; i < 16; ++i) a[i] = 0.f;
#pragma unroll
    for (int dc = 0; dc < 8; ++dc)
      a = __builtin_amdgcn_mfma_f32_32x32x16_f16(kf[(size_t)dc*64], qf[dc], a, 0, 0, 0);

    // mask + p = exp(s-m)/L -> ps[q=ln][w*32 + col]
#pragma unroll
    for (int mm = 0; mm < 4; ++mm){
      const uint4v dw = *(const uint4v*)(mrow + kt*32 + mm*8 + h*4);
#pragma unroll
      for (int aa = 0; aa < 4; ++aa){
        const int r = mm*4 + aa;
        const float s = ((dw[aa] >> ln) & 1u) ? a[r] : -1.0e30f;
        a[r] = __expf(s - m) * rinv;
      }
    }
#pragma unroll
    for (int gg = 0; gg < 4; ++gg){
      const int c = w*32 + gg*8 + h*4;
      float2 e0, e1;
      e0.x = a[4*gg+0]; e0.y = a[4*gg+1];
      e1.x = a[4*gg+2]; e1.y = a[4*gg+3];
      *(float2*)&ps[ln][c]   = e0;
      *(float2*)&ps[ln][c+2] = e1;
    }
    __syncthreads();

    // stream out: wave w stores rows w*4..w*4+3, 1KB contiguous per row
#pragma unroll
    for (int i = 0; i < 4; ++i){
      const int row = w*4 + i;
      const f32x4v v4 = *(const f32x4v*)&ps[row][l*4];
      __builtin_nontemporal_store(v4,
          (f32x4v*)(pbase + (size_t)row*Sn + g*256 + l*4));
    }

    // PV for this wave's column slice: B-frag from ps, A-frag = packed V^T
#pragma unroll
    for (int t16 = 0; t16 < 2; ++t16){
      const int c = w*32 + t16*16 + h*8;
      const float2 b0 = *(const float2*)&ps[ln][c];
      const float2 b1 = *(const float2*)&ps[ln][c+2];
      const float2 b2 = *(const float2*)&ps[ln][c+4];
      const float2 b3 = *(const float2*)&ps[ln][c+6];
      int4 bi;
      bi.x = pk_f16(b0.x, b0.y);
      bi.y = pk_f16(b1.x, b1.y);
      bi.z = pk_f16(b2.x, b2.y);
      bi.w = pk_f16(b3.x, b3.y);
      const half8 bf = __builtin_bit_cast(half8, bi);
      const half8* vf = vp + (((size_t)bh*128 + (kt*2 + t16))*4)*64 + l;
#pragma unroll
      for (int dt = 0; dt < 4; ++dt)
        oacc[dt] = __builtin_amdgcn_mfma_f32_32x32x16_f16(vf[(size_t)dt*64], bf, oacc[dt], 0, 0, 0);
    }
    __syncthreads();
  }

  // cross-wave reduce out^T, then coalesced nt store
#pragma unroll
  for (int dt = 0; dt < 4; ++dt){
#pragma unroll
    for (int r = 0; r < 16; ++r){
      const int d = dt*32 + (r&3) + 8*(r>>2) + h*4;
      atomicAdd(&lds_out[d*33 + ln], oacc[dt][r]);
    }
  }
  __syncthreads();
  const size_t obase = ((size_t)bh*Sn + qb*32)*Dn;
#pragma unroll
  for (int it = 0; it < 2; ++it){
    const int idx = it*512 + tid;        // float4 chunk id, 1024 total
    const int qq  = idx >> 5;            // 32 chunks per 128-float row
    const int c4  = (idx & 31) * 4;
    f32x4v v4;
    v4.x = lds_out[(c4+0)*33 + qq];
    v4.y = lds_out[(c4+1)*33 + qq];
    v4.z = lds_out[(c4+2)*33 + qq];
    v4.w = lds_out[(c4+3)*33 + qq];
    __builtin_nontemporal_store(v4, (f32x4v*)(out + obase + (size_t)qq*Dn + c4));
  }
}

// ---------------- launch ----------------

extern "C" void kernel_launch(void* const* d_in, const int* in_sizes, int n_in,
                              void* d_out, int out_size, void* d_ws, size_t ws_size,
                              hipStream_t stream)
{
  const float* dq = (const float*)d_in[0];
  const float* dk = (const float*)d_in[1];
  const float* dv = (const float*)d_in[2];
  const int*   dm = (const int*)d_in[3];

  char* ws = (char*)d_ws;
  float2*   tab = (float2*)ws;                                  // 1 MiB
  half8*    qp  = (half8*)(ws + (size_t)(1u<<20));              // 32 MiB
  half8*    kp  = (half8*)(ws + (size_t)(1u<<20) + ((size_t)32<<20));
  half8*    vp  = (half8*)(ws + (size_t)(1u<<20) + ((size_t)64<<20));
  unsigned* mtb = (unsigned*)(ws + (size_t)(1u<<20) + ((size_t)96<<20));   // 0.5 MiB
  float2*   mLb = (float2*)(ws + (size_t)(1u<<20) + ((size_t)97<<20));     // 1 MiB

  float* out  = (float*)d_out;
  float* pout = out + (size_t)Bn*Hn*Sn*Dn;

  k_rope_table<<<512,  256, 0, stream>>>(tab);
  k_pack_qk   <<<8192, 256, 0, stream>>>(dq, dk, tab, qp, kp);
  k_pack_v    <<<8192, 256, 0, stream>>>(dv, vp);
  k_maskbits  <<<512,  256, 0, stream>>>(dm, mtb);
  attn_stats  <<<512,  512, 0, stream>>>(qp, kp, mtb, mLb);
  attn_pv     <<<4096, 512, 0, stream>>>(qp, kp, vp, mtb, mLb, out, pout);
}